// Round 1
// baseline (218.592 us; speedup 1.0000x reference)
//
#include <hip/hip_runtime.h>

#define NUM_NODES   120000
#define NUM_MOVABLE 100000
#define NUM_NETS    100000
#define NUM_PINS    400000
#define NBX 256
#define NBY 256
#define GRID (NBX*NBY)

__device__ __constant__ float c_dummy; // keep compiler happy if needed

constexpr float BSX    = 1000.0f / 256.0f;   // 3.90625 exact
constexpr float BSY    = 1000.0f / 256.0f;
constexpr float INV_BS = 256.0f / 1000.0f;
constexpr float BIN_AREA = BSX * BSY;
constexpr float EPSV = 1e-6f;

// Grid layout in workspace (floats):
// 0: P_h  (point)        1: Cx_h (needs y-prefix)  2: Cy_h (needs x-prefix)  3: Q_h (y then x prefix)
// 4: P_v                 5: Cx_v                   6: Cy_v                   7: Q_v
// 8: util

__device__ __forceinline__ void splat4(float* __restrict__ P, float* __restrict__ CX,
                                       float* __restrict__ CY, float* __restrict__ Q,
                                       int bx, int by, float w, float rx, float ry) {
    int idx = bx * NBY + by;
    atomicAdd(P  + idx, w * rx * ry);
    atomicAdd(CX + idx, w * rx * BSY);
    atomicAdd(CY + idx, w * BSX * ry);
    atomicAdd(Q  + idx, w * BSX * BSY);
}

__global__ void net_splat(const float* __restrict__ pin_pos,
                          const int* __restrict__ netpin_start,
                          const int* __restrict__ flat_netpin,
                          float* __restrict__ W) {
    int n = blockIdx.x * blockDim.x + threadIdx.x;
    if (n >= NUM_NETS) return;
    int s = netpin_start[n], e = netpin_start[n + 1];
    if (e <= s) return;  // empty net -> invalid -> zero contribution
    float xmn = 3.4e38f, xmx = -3.4e38f, ymn = 3.4e38f, ymx = -3.4e38f;
    for (int i = s; i < e; ++i) {
        int p = flat_netpin[i];
        float px = pin_pos[p];
        float py = pin_pos[NUM_PINS + p];
        xmn = fminf(xmn, px); xmx = fmaxf(xmx, px);
        ymn = fminf(ymn, py); ymx = fmaxf(ymx, py);
    }
    float span_x = xmx - xmn, span_y = ymx - ymn;
    float coef_h = (span_y > EPSV) ? 1.0f / span_y : 0.0f;
    float coef_v = (span_x > EPSV) ? 1.0f / span_x : 0.0f;
    if (coef_h == 0.0f && coef_v == 0.0f) return;

    int bxl = min((int)(xmn * INV_BS), NBX - 1);
    int bxh = min((int)(xmx * INV_BS), NBX - 1);
    int byl = min((int)(ymn * INV_BS), NBY - 1);
    int byh = min((int)(ymx * INV_BS), NBY - 1);
    float rxl = (float)(bxl + 1) * BSX - xmn;
    float rxh = (float)(bxh + 1) * BSX - xmx;
    float ryl = (float)(byl + 1) * BSY - ymn;
    float ryh = (float)(byh + 1) * BSY - ymx;

    // ox (X) oy = (s_xl - s_xh) (X) (s_yl - s_yh)  -> 4 signed corner splats
    if (coef_h > 0.0f) {
        float* P  = W;             float* CX = W + GRID;
        float* CY = W + 2 * GRID;  float* Q  = W + 3 * GRID;
        splat4(P, CX, CY, Q, bxl, byl,  coef_h, rxl, ryl);
        splat4(P, CX, CY, Q, bxl, byh, -coef_h, rxl, ryh);
        splat4(P, CX, CY, Q, bxh, byl, -coef_h, rxh, ryl);
        splat4(P, CX, CY, Q, bxh, byh,  coef_h, rxh, ryh);
    }
    if (coef_v > 0.0f) {
        float* P  = W + 4 * GRID;  float* CX = W + 5 * GRID;
        float* CY = W + 6 * GRID;  float* Q  = W + 7 * GRID;
        splat4(P, CX, CY, Q, bxl, byl,  coef_v, rxl, ryl);
        splat4(P, CX, CY, Q, bxl, byh, -coef_v, rxl, ryh);
        splat4(P, CX, CY, Q, bxh, byl, -coef_v, rxh, ryl);
        splat4(P, CX, CY, Q, bxh, byh,  coef_v, rxh, ryh);
    }
}

// Exclusive prefix along y (inner dim) for grids 1,3,5,7. One thread per (grid,row).
__global__ void prefix_y(float* __restrict__ W) {
    int t = blockIdx.x * blockDim.x + threadIdx.x;
    if (t >= 4 * NBX) return;
    const int gids[4] = {1, 3, 5, 7};
    int g = gids[t >> 8];
    int x = t & (NBX - 1);
    float* row = W + g * GRID + x * NBY;
    float sum = 0.0f;
    for (int y = 0; y < NBY; ++y) {
        float v = row[y];
        row[y] = sum;
        sum += v;
    }
}

// Exclusive prefix along x (outer dim) for grids 2,3,6,7. One thread per (grid,col).
__global__ void prefix_x(float* __restrict__ W) {
    int t = blockIdx.x * blockDim.x + threadIdx.x;
    if (t >= 4 * NBY) return;
    const int gids[4] = {2, 3, 6, 7};
    int g = gids[t >> 8];
    int y = t & (NBY - 1);
    float* col = W + g * GRID + y;
    float sum = 0.0f;
    for (int x = 0; x < NBX; ++x) {
        float v = col[x * NBY];
        col[x * NBY] = sum;
        sum += v;
    }
}

__global__ void make_util(float* __restrict__ W) {
    int i = blockIdx.x * blockDim.x + threadIdx.x;
    if (i >= GRID) return;
    float H = W[i] + W[GRID + i] + W[2 * GRID + i] + W[3 * GRID + i];
    float V = W[4 * GRID + i] + W[5 * GRID + i] + W[6 * GRID + i] + W[7 * GRID + i];
    float u = fmaxf(H, V) * (1.0f / (BIN_AREA * 1.5f));
    u = fminf(fmaxf(u, 0.5f), 2.0f);
    W[8 * GRID + i] = u;
}

__global__ void node_area(const float* __restrict__ pos,
                          const float* __restrict__ nsx,
                          const float* __restrict__ nsy,
                          const float* __restrict__ util,
                          float* __restrict__ out) {
    int m = blockIdx.x * blockDim.x + threadIdx.x;
    if (m >= NUM_MOVABLE) return;
    float xl = pos[m];
    float yl = pos[NUM_NODES + m];
    float xh = xl + nsx[m];
    float yh = yl + nsy[m];
    int bx0 = max(0, min((int)(xl * INV_BS), NBX - 1));
    int bx1 = max(0, min((int)(xh * INV_BS), NBX - 1));
    int by0 = max(0, min((int)(yl * INV_BS), NBY - 1));
    int by1 = max(0, min((int)(yh * INV_BS), NBY - 1));
    float acc = 0.0f;
    for (int bx = bx0; bx <= bx1; ++bx) {
        float ox = fminf(xh, (float)(bx + 1) * BSX) - fmaxf(xl, (float)bx * BSX);
        if (ox <= 0.0f) continue;
        const float* urow = util + bx * NBY;
        float inner = 0.0f;
        for (int by = by0; by <= by1; ++by) {
            float oy = fminf(yh, (float)(by + 1) * BSY) - fmaxf(yl, (float)by * BSY);
            if (oy > 0.0f) inner += oy * urow[by];
        }
        acc += ox * inner;
    }
    out[m] = acc;
}

extern "C" void kernel_launch(void* const* d_in, const int* in_sizes, int n_in,
                              void* d_out, int out_size, void* d_ws, size_t ws_size,
                              hipStream_t stream) {
    const float* pos          = (const float*)d_in[0];
    const float* pin_pos      = (const float*)d_in[1];
    const float* node_size_x  = (const float*)d_in[2];
    const float* node_size_y  = (const float*)d_in[3];
    const int*   netpin_start = (const int*)d_in[4];
    const int*   flat_netpin  = (const int*)d_in[5];
    float* W   = (float*)d_ws;
    float* out = (float*)d_out;

    // zero the 8 accumulator grids (ws is poisoned 0xAA before every launch)
    hipMemsetAsync(W, 0, (size_t)8 * GRID * sizeof(float), stream);

    net_splat<<<(NUM_NETS + 255) / 256, 256, 0, stream>>>(pin_pos, netpin_start, flat_netpin, W);
    prefix_y<<<4, 256, 0, stream>>>(W);
    prefix_x<<<4, 256, 0, stream>>>(W);
    make_util<<<GRID / 256, 256, 0, stream>>>(W);
    node_area<<<(NUM_MOVABLE + 255) / 256, 256, 0, stream>>>(
        pos, node_size_x, node_size_y, W + 8 * GRID, out);
}